// Round 9
// baseline (382.159 us; speedup 1.0000x reference)
//
#include <hip/hip_runtime.h>
#include <hip/hip_bf16.h>
#include <stdint.h>

#define S_LEN 2048
#define NB 2
#define NH 16
#define HDIM 128
#define RDIM 64
#define DF 192          // HDIM + RDIM
#define MROWS 4096      // NB * S_LEN

typedef __bf16 bf16_t;
typedef __attribute__((ext_vector_type(8))) __bf16 bf16x8;
typedef __attribute__((ext_vector_type(4))) __bf16 bf16x4;
typedef __attribute__((ext_vector_type(4))) float f32x4;
typedef __attribute__((ext_vector_type(4))) float float4v;

__device__ __forceinline__ void gload_lds16(const bf16_t* g, bf16_t* l) {
  __builtin_amdgcn_global_load_lds(
      (const __attribute__((address_space(1))) void*)g,
      (__attribute__((address_space(3))) void*)l, 16, 0, 0);
}

// ---------------- convert f32 -> bf16 (contiguous) ----------------
__global__ __launch_bounds__(256) void convert_bf16(const float* __restrict__ in,
                                                    bf16_t* __restrict__ out, int n4) {
  int i = blockIdx.x * 256 + threadIdx.x;
  if (i >= n4) return;
  float4v v = *reinterpret_cast<const float4v*>(&in[(size_t)i * 4]);
  bf16x4 o;
  o[0] = (bf16_t)v[0]; o[1] = (bf16_t)v[1]; o[2] = (bf16_t)v[2]; o[3] = (bf16_t)v[3];
  *reinterpret_cast<bf16x4*>(&out[(size_t)i * 4]) = o;
}

// ---------------- fused transpose: all 8 weights in one launch ----------------
struct TrDesc { const float* src; bf16_t* dst; int K; int N; int nbx; int base; };
struct TrPack { TrDesc d[8]; };

__global__ __launch_bounds__(256) void transpose_all(TrPack p) {
  __shared__ float t[64][65];
  const int bid = blockIdx.x;
  int m = 0;
#pragma unroll
  for (int i = 1; i < 8; ++i) m += (bid >= p.d[i].base);
  const TrDesc td = p.d[m];
  const int local = bid - td.base;
  const int n0 = (local % td.nbx) * 64, k0 = (local / td.nbx) * 64;
  const int tx = threadIdx.x & 63, ty = threadIdx.x >> 6;
#pragma unroll
  for (int i = ty; i < 64; i += 4)
    t[i][tx] = td.src[(size_t)(k0 + i) * td.N + n0 + tx];
  __syncthreads();
#pragma unroll
  for (int i = ty; i < 64; i += 4)
    td.dst[(size_t)(n0 + i) * td.K + k0 + tx] = (bf16_t)t[tx][i];
}

// ---------------- pipelined GEMM: C(M,N) = A(M,K) * Bt(N,K)^T ----------------
// 256x128 tile, BK=64, 8 waves (512 thr), per-wave 64x64 (acc[4][4]).
// 3-buffer LDS (144 KB), depth-2 prefetch, ONE s_barrier per K-tile,
// counted vmcnt(6) (tile t+1 stays in flight across the barrier).
// A/B tiles XOR-swizzled (16B chunk ^= row&7): pre-swizzled GLOBAL source +
// linear LDS dest (gload_lds rule) + swizzled LDS read. 2-way conflicts only.
// MODE 1: f32 out + bias
// MODE 5: fused xb@[Wlq|Wkv|Wkr]; MODE 6: fused cq@[Wq|Wqr]; MODE 7: ckv@[Wk|Wv]
struct EpiParams {
  bf16_t* o0;
  bf16_t* o1;
  bf16_t* o2;
  float* outf;
  const float* bias;
  const float* cosb;
  const float* sinb;
};

template <int MODE>
__device__ __forceinline__ void gemm8p_body(const bf16_t* __restrict__ A,
                                            const bf16_t* __restrict__ Bt,
                                            int N, int K, int m0, int n0,
                                            bf16_t (*Ab)[256 * 64],
                                            bf16_t (*Bb)[128 * 64], EpiParams ep) {
  const int tid = threadIdx.x;
  const int lane = tid & 63, w = tid >> 6;    // 8 waves: 4M x 2N
  const int l15 = lane & 15, lg = lane >> 4;
  const int mw = (w >> 1) * 64, nw = (w & 1) * 64;
  const int nt = K >> 6;

  auto stage = [&](int t, int buf) {
    const int k0 = t << 6;
#pragma unroll
    for (int j = 0; j < 4; ++j) {             // A: 256 rows x 128B = 2048 slots
      const int s = j * 512 + tid;
      const int row = s >> 3, c = s & 7;
      const int cs = c ^ (row & 7);
      gload_lds16(A + (size_t)(m0 + row) * K + k0 + cs * 8, &Ab[buf][s * 8]);
    }
#pragma unroll
    for (int j = 0; j < 2; ++j) {             // B: 128 rows x 128B = 1024 slots
      const int s = j * 512 + tid;
      const int row = s >> 3, c = s & 7;
      const int cs = c ^ (row & 7);
      gload_lds16(Bt + (size_t)(n0 + row) * K + k0 + cs * 8, &Bb[buf][s * 8]);
    }
  };

  f32x4 acc[4][4] = {};
  stage(0, 0);
  stage(1, 1);                                // 12 loads in flight

  for (int t = 0; t < nt; ++t) {
    const int cur = t % 3;
    if (t + 1 < nt) {
      asm volatile("s_waitcnt vmcnt(6)" ::: "memory");   // tile t landed; t+1 in flight
    } else {
      asm volatile("s_waitcnt vmcnt(0)" ::: "memory");   // final drain
    }
    __builtin_amdgcn_s_barrier();             // tile t visible; buf (t+2)%3 free
    __builtin_amdgcn_sched_barrier(0);
    if (t + 2 < nt) stage(t + 2, (t + 2) % 3);

    __builtin_amdgcn_s_setprio(1);
#pragma unroll
    for (int kk = 0; kk < 2; ++kk) {
      const int c = kk * 4 + lg;
      bf16x8 a[4], b[4];
#pragma unroll
      for (int i = 0; i < 4; ++i) {
        const int r = mw + i * 16 + l15;
        a[i] = *reinterpret_cast<const bf16x8*>(&Ab[cur][r * 64 + ((c ^ (r & 7)) << 3)]);
      }
#pragma unroll
      for (int j = 0; j < 4; ++j) {
        const int r = nw + j * 16 + l15;
        b[j] = *reinterpret_cast<const bf16x8*>(&Bb[cur][r * 64 + ((c ^ (r & 7)) << 3)]);
      }
#pragma unroll
      for (int i = 0; i < 4; ++i)
#pragma unroll
        for (int j = 0; j < 4; ++j)
          acc[i][j] = __builtin_amdgcn_mfma_f32_16x16x32_bf16(a[i], b[j], acc[i][j], 0, 0, 0);
    }
    __builtin_amdgcn_s_setprio(0);
  }

#pragma unroll
  for (int i = 0; i < 4; ++i)
#pragma unroll
    for (int j = 0; j < 4; ++j) {
      const int col = n0 + nw + j * 16 + l15;
#pragma unroll
      for (int r = 0; r < 4; ++r) {
        const int row = m0 + mw + i * 16 + lg * 4 + r;
        float v = acc[i][j][r];
        const int b = row >> 11, s = row & 2047;
        if constexpr (MODE == 1) {
          ep.outf[(size_t)row * N + col] = v + ep.bias[col];
        } else if constexpr (MODE == 5) {
          if (col < 1536) {
            ep.o0[(size_t)row * 1536 + col] = (bf16_t)v;
          } else if (col < 2048) {
            ep.o1[(size_t)row * 512 + (col - 1536)] = (bf16_t)v;
          } else {
            const int c2 = col - 2048;
            float vb = v + ep.bias[c2];
            float other = __shfl_xor(vb, 1, 64);
            const int h = c2 >> 6, dr = c2 & 63;
            const int fi = dr >> 1;
            const float c = ep.cosb[s * 32 + fi];
            const float sn = ep.sinb[s * 32 + fi];
            const float o = (c2 & 1) ? (other * sn + vb * c) : (vb * c - other * sn);
            ep.o2[(((size_t)(b * NH + h)) * S_LEN + s) * DF + 128 + dr] = (bf16_t)o;
          }
        } else if constexpr (MODE == 6) {
          if (col < 2048) {
            const int h = col >> 7, d = col & 127;
            ep.o0[(((size_t)(b * NH + h)) * S_LEN + s) * DF + d] = (bf16_t)v;
          } else {
            const int c2 = col - 2048;
            float vb = v + ep.bias[c2];
            float other = __shfl_xor(vb, 1, 64);
            const int h = c2 >> 6, dr = c2 & 63;
            const int fi = dr >> 1;
            const float c = ep.cosb[s * 32 + fi];
            const float sn = ep.sinb[s * 32 + fi];
            const float o = (c2 & 1) ? (other * sn + vb * c) : (vb * c - other * sn);
            ep.o0[(((size_t)(b * NH + h)) * S_LEN + s) * DF + 128 + dr] = (bf16_t)o;
          }
        } else {  // MODE 7
          if (col < 2048) {
            const int h = col >> 7, d = col & 127;
            ep.o0[(((size_t)(b * NH + h)) * S_LEN + s) * DF + d] = (bf16_t)v;
          } else {
            const int c2 = col - 2048;
            const int h = c2 >> 7, d = c2 & 127;
            ep.o1[(((size_t)(b * NH + h)) * HDIM + d) * S_LEN + s] = (bf16_t)v;
          }
        }
      }
    }
}

template <int MODE>
__global__ __launch_bounds__(512, 2) void gemm8p(const bf16_t* __restrict__ A,
                                                 const bf16_t* __restrict__ Bt,
                                                 int N, int K, EpiParams ep) {
  __shared__ alignas(16) bf16_t Ab[3][256 * 64];
  __shared__ alignas(16) bf16_t Bb[3][128 * 64];
  const int nwg = gridDim.x;
  int f = blockIdx.x;
  f = (f & 7) * (nwg >> 3) + (f >> 3);        // T1 XCD swizzle (nwg % 8 == 0)
  const int nbx = N >> 7;
  const int m0 = (f / nbx) * 256, n0 = (f % nbx) * 128;
  gemm8p_body<MODE>(A, Bt, N, K, m0, n0, Ab, Bb, ep);
}

// Fused: blocks [0,384) MODE 6 (N=3072,K=1536); [384,896) MODE 7 (N=4096,K=512).
__global__ __launch_bounds__(512, 2) void gemm8p67(const bf16_t* __restrict__ A6,
                                                   const bf16_t* __restrict__ Bt6,
                                                   const bf16_t* __restrict__ A7,
                                                   const bf16_t* __restrict__ Bt7,
                                                   EpiParams ep6, EpiParams ep7) {
  __shared__ alignas(16) bf16_t Ab[3][256 * 64];
  __shared__ alignas(16) bf16_t Bb[3][128 * 64];
  const int bid = blockIdx.x;
  if (bid < 384) {
    int f = (bid & 7) * 48 + (bid >> 3);
    const int m0 = (f / 24) * 256, n0 = (f % 24) * 128;
    gemm8p_body<6>(A6, Bt6, 3072, 1536, m0, n0, Ab, Bb, ep6);
  } else {
    int b2 = bid - 384;
    int f = (b2 & 7) * 64 + (b2 >> 3);
    const int m0 = (f / 32) * 256, n0 = (f % 32) * 128;
    gemm8p_body<7>(A7, Bt7, 4096, 512, m0, n0, Ab, Bb, ep7);
  }
}

// ---------------- flash attention (causal), swapped softmax, 32q/wave ----------------
// (unchanged from r8: 4 waves x 32 q-rows, swapped QK^T, defer-max, 56 KB LDS)
__global__ __launch_bounds__(256, 2) void attn_fwd(const bf16_t* __restrict__ qf,
                                                   const bf16_t* __restrict__ kf,
                                                   const bf16_t* __restrict__ vT,
                                                   bf16_t* __restrict__ att) {
  const int tid = threadIdx.x;
  const int lane = tid & 63, w = tid >> 6;   // w: 0..3
  const int l15 = lane & 15, lg = lane >> 4;
  const int l = blockIdx.x;                  // 0..511
  const int bh = (l & 7) * 4 + ((l >> 3) & 3);
  const int qchunk = l >> 5;                 // 0..15
  const int qb0 = (15 - qchunk) * 128;
  const int q0 = qb0 + w * 32;
  const float scale = 0.07216878364870322f;  // 1/sqrt(192)

  __shared__ alignas(16) bf16_t Ks[64 * 192];
  __shared__ alignas(16) bf16_t Vs[128 * 64];
  __shared__ alignas(16) bf16_t Ps[4 * 2048];

  bf16x8 qfr[2][6];
#pragma unroll
  for (int mf = 0; mf < 2; ++mf) {
    const bf16_t* qptr = qf + ((size_t)bh * S_LEN + q0 + mf * 16 + l15) * DF + lg * 8;
#pragma unroll
    for (int d = 0; d < 6; ++d)
      qfr[mf][d] = *reinterpret_cast<const bf16x8*>(qptr + d * 32);
  }

  f32x4 o[2][8] = {};
  float mrun[2] = {-1e30f, -1e30f}, lsum[2] = {0.0f, 0.0f};

  const bf16_t* kb0 = kf + (size_t)bh * S_LEN * DF;
  const bf16_t* vb0 = vT + (size_t)bh * HDIM * S_LEN;
  const int njt = qb0 / 64 + 2;
  const int wslot = tid & ~63;

  for (int jt = 0; jt < njt; ++jt) {
    const int j0 = jt * 64;
    __syncthreads();
    const bf16_t* kTile = kb0 + (size_t)j0 * DF;
#pragma unroll
    for (int i = 0; i < 6; ++i) {
      const int s = i * 256 + tid;
      const int row = s / 24;
      const int c = s - row * 24;
      const int cs = c ^ (row & 7);
      gload_lds16(kTile + (size_t)row * DF + cs * 8,
                  Ks + (size_t)(i * 256 + wslot) * 8);
    }
    const bf16_t* vTile = vb0 + j0;
#pragma unroll
    for (int i = 0; i < 4; ++i) {
      const int s = i * 256 + tid;
      const int row = s >> 3;
      const int c = s & 7;
      const int cs = c ^ (row & 7);
      gload_lds16(vTile + (size_t)row * S_LEN + cs * 8,
                  Vs + (size_t)(i * 256 + wslot) * 8);
    }
    __syncthreads();

    if (j0 > q0 + 31) continue;

    f32x4 sa[2][4] = {};
    __builtin_amdgcn_s_setprio(1);
#pragma unroll
    for (int jf = 0; jf < 4; ++jf) {
      const int krow = jf * 16 + l15;
      const int ksw = krow & 7;
#pragma unroll
      for (int d = 0; d < 6; ++d) {
        const int kc = (4 * d + lg) ^ ksw;
        bf16x8 kfr = *reinterpret_cast<const bf16x8*>(&Ks[krow * 192 + kc * 8]);
#pragma unroll
        for (int mf = 0; mf < 2; ++mf)
          sa[mf][jf] =
              __builtin_amdgcn_mfma_f32_16x16x32_bf16(kfr, qfr[mf][d], sa[mf][jf], 0, 0, 0);
      }
    }
    __builtin_amdgcn_s_setprio(0);

#pragma unroll
    for (int mf = 0; mf < 2; ++mf) {
      const int qi = q0 + mf * 16 + l15;
      const bool full = (j0 + 63 <= q0 + mf * 16);
      float sv[16];
#pragma unroll
      for (int jf = 0; jf < 4; ++jf)
#pragma unroll
        for (int r = 0; r < 4; ++r) {
          float x = sa[mf][jf][r] * scale;
          if (!full) {
            const int j = j0 + jf * 16 + lg * 4 + r;
            if (j > qi) x = -1e30f;
          }
          sv[jf * 4 + r] = x;
        }

      float a8[8];
#pragma unroll
      for (int i = 0; i < 8; ++i) a8[i] = fmaxf(sv[i], sv[i + 8]);
#pragma unroll
      for (int i = 0; i < 4; ++i) a8[i] = fmaxf(a8[i], a8[i + 4]);
      float mx = fmaxf(fmaxf(a8[0], a8[1]), fmaxf(a8[2], a8[3]));
      mx = fmaxf(mx, __shfl_xor(mx, 16, 64));
      mx = fmaxf(mx, __shfl_xor(mx, 32, 64));

      if (__any(mx > mrun[mf] + 8.0f)) {
        const float mn = fmaxf(mrun[mf], mx);
        const float alpha = __expf(mrun[mf] - mn);
        mrun[mf] = mn;
        lsum[mf] *= alpha;
        float af[4];
#pragma unroll
        for (int r = 0; r < 4; ++r) af[r] = __shfl(alpha, lg * 4 + r, 16);
#pragma unroll
        for (int dt = 0; dt < 8; ++dt)
#pragma unroll
          for (int r = 0; r < 4; ++r) o[mf][dt][r] *= af[r];
      }

#pragma unroll
      for (int i = 0; i < 16; ++i) sv[i] = __expf(sv[i] - mrun[mf]);
      float s8[8];
#pragma unroll
      for (int i = 0; i < 8; ++i) s8[i] = sv[i] + sv[i + 8];
#pragma unroll
      for (int i = 0; i < 4; ++i) s8[i] = s8[i] + s8[i + 4];
      float sm = (s8[0] + s8[1]) + (s8[2] + s8[3]);
      sm += __shfl_xor(sm, 16, 64);
      sm += __shfl_xor(sm, 32, 64);
      lsum[mf] += sm;

#pragma unroll
      for (int jf = 0; jf < 4; ++jf) {
        bf16x4 pk;
#pragma unroll
        for (int r = 0; r < 4; ++r) pk[r] = (bf16_t)sv[jf * 4 + r];
        const int key = jf * 16 + lg * 4;
        *reinterpret_cast<bf16x4*>(
            &Ps[w * 2048 + mf * 1024 + l15 * 64 + (key ^ ((l15 & 7) << 3))]) = pk;
      }
    }
    asm volatile("s_waitcnt lgkmcnt(0)" ::: "memory");
    __builtin_amdgcn_sched_barrier(0);
    bf16x8 pfr[2][2];
#pragma unroll
    for (int mf = 0; mf < 2; ++mf)
#pragma unroll
      for (int jk = 0; jk < 2; ++jk)
        pfr[mf][jk] = *reinterpret_cast<const bf16x8*>(
            &Ps[w * 2048 + mf * 1024 + l15 * 64 + (((jk * 4 + lg) ^ (l15 & 7)) << 3)]);

    __builtin_amdgcn_s_setprio(1);
#pragma unroll
    for (int dt = 0; dt < 8; ++dt) {
      const int vrow = dt * 16 + l15;
      const int vsw = vrow & 7;
#pragma unroll
      for (int jk = 0; jk < 2; ++jk) {
        const int vc = (jk * 4 + lg) ^ vsw;
        bf16x8 vfr = *reinterpret_cast<const bf16x8*>(&Vs[vrow * 64 + vc * 8]);
#pragma unroll
        for (int mf = 0; mf < 2; ++mf)
          o[mf][dt] =
              __builtin_amdgcn_mfma_f32_16x16x32_bf16(pfr[mf][jk], vfr, o[mf][dt], 0, 0, 0);
      }
    }
    __builtin_amdgcn_s_setprio(0);
  }

  const int b = bh >> 4, h = bh & 15;
#pragma unroll
  for (int mf = 0; mf < 2; ++mf) {
    const float inv = 1.0f / lsum[mf];
    float iv[4];
#pragma unroll
    for (int r = 0; r < 4; ++r) iv[r] = __shfl(inv, lg * 4 + r, 16);
#pragma unroll
    for (int dt = 0; dt < 8; ++dt)
#pragma unroll
      for (int r = 0; r < 4; ++r) {
        const int s = q0 + mf * 16 + lg * 4 + r;
        att[((size_t)b * S_LEN + s) * 2048 + h * 128 + dt * 16 + l15] =
            (bf16_t)(o[mf][dt][r] * iv[r]);
      }
  }
}

// ---------------- host launch ----------------
extern "C" void kernel_launch(void* const* d_in, const int* in_sizes, int n_in,
                              void* d_out, int out_size, void* d_ws, size_t ws_size,
                              hipStream_t stream) {
  const float* x    = (const float*)d_in[0];
  const float* fcos = (const float*)d_in[1];
  const float* fsin = (const float*)d_in[2];
  const float* Wkv  = (const float*)d_in[3];
  const float* Wlq  = (const float*)d_in[4];
  const float* Wq   = (const float*)d_in[5];
  const float* Wk   = (const float*)d_in[6];
  const float* Wv   = (const float*)d_in[7];
  const float* Wqr  = (const float*)d_in[8];
  const float* bqr  = (const float*)d_in[9];
  const float* Wkr  = (const float*)d_in[10];
  const float* bkr  = (const float*)d_in[11];
  const float* Wo   = (const float*)d_in[12];
  const float* bo   = (const float*)d_in[13];
  float* out = (float*)d_out;

  char* ws = (char*)d_ws;
  size_t off = 0;
  auto alloc = [&](size_t bytes) {
    void* p = ws + off;
    off += (bytes + 255) & ~(size_t)255;
    return p;
  };
  bf16_t* xb    = (bf16_t*)alloc((size_t)MROWS * 2048 * 2);
  bf16_t* WcatA = (bf16_t*)alloc((size_t)3072 * 2048 * 2);  // [Wlq|Wkv|Wkr]^T, K=2048
  bf16_t* WcatB = (bf16_t*)alloc((size_t)3072 * 1536 * 2);  // [Wq|Wqr]^T,     K=1536
  bf16_t* WcatC = (bf16_t*)alloc((size_t)4096 * 512 * 2);   // [Wk|Wv]^T,      K=512
  bf16_t* WoT   = (bf16_t*)alloc((size_t)2048 * 2048 * 2);
  bf16_t* cq    = (bf16_t*)alloc((size_t)MROWS * 1536 * 2);
  bf16_t* ckv   = (bf16_t*)alloc((size_t)MROWS * 512 * 2);
  bf16_t* qfb   = (bf16_t*)alloc((size_t)NB * NH * S_LEN * DF * 2);
  bf16_t* kfb   = (bf16_t*)alloc((size_t)NB * NH * S_LEN * DF * 2);
  bf16_t* vTb   = (bf16_t*)alloc((size_t)NB * NH * HDIM * S_LEN * 2);
  bf16_t* attb  = (bf16_t*)alloc((size_t)MROWS * 2048 * 2);

  // 1. convert x
  {
    int n4 = (MROWS * 2048) / 4;
    convert_bf16<<<dim3((n4 + 255) / 256), dim3(256), 0, stream>>>(x, xb, n4);
  }
  // 2. all 8 transposes in one launch
  {
    TrPack p;
    int base = 0;
    auto set = [&](int i, const float* s, bf16_t* d, int K, int N) {
      p.d[i] = {s, d, K, N, N / 64, base};
      base += (N / 64) * (K / 64);
    };
    set(0, Wlq, WcatA, 2048, 1536);
    set(1, Wkv, WcatA + (size_t)1536 * 2048, 2048, 512);
    set(2, Wkr, WcatA + (size_t)2048 * 2048, 2048, 1024);
    set(3, Wq,  WcatB, 1536, 2048);
    set(4, Wqr, WcatB + (size_t)2048 * 1536, 1536, 1024);
    set(5, Wk,  WcatC, 512, 2048);
    set(6, Wv,  WcatC + (size_t)2048 * 512, 512, 2048);
    set(7, Wo,  WoT, 2048, 2048);
    transpose_all<<<dim3(base), dim3(256), 0, stream>>>(p);
  }

  EpiParams ep{}, ep2{};

  // 3. fused: [cq | ckv | kr-rope->kf] = xb @ WcatA^T   (N=3072, K=2048)
  ep = {cq, ckv, kfb, nullptr, bkr, fcos, fsin};
  gemm8p<5><<<dim3(384), dim3(512), 0, stream>>>(xb, WcatA, 3072, 2048, ep);
  // 4+5. fused single launch: {q,qr->qf} and {k->kf, v->vT}
  ep  = {qfb, nullptr, nullptr, nullptr, bqr, fcos, fsin};
  ep2 = {kfb, vTb, nullptr, nullptr, nullptr, nullptr, nullptr};
  gemm8p67<<<dim3(896), dim3(512), 0, stream>>>(cq, WcatB, ckv, WcatC, ep, ep2);
  // 6. attention
  attn_fwd<<<dim3(512), dim3(256), 0, stream>>>(qfb, kfb, vTb, attb);
  // 7. out = att @ Wo + bo  (f32)
  ep = {nullptr, nullptr, nullptr, out, bo, nullptr, nullptr};
  gemm8p<1><<<dim3(256), dim3(512), 0, stream>>>(attb, WoT, 2048, 2048, ep);
}

// Round 10
// 346.723 us; speedup vs baseline: 1.1022x; 1.1022x over previous
//
#include <hip/hip_runtime.h>
#include <hip/hip_bf16.h>
#include <stdint.h>

#define S_LEN 2048
#define NB 2
#define NH 16
#define HDIM 128
#define RDIM 64
#define DF 192          // HDIM + RDIM
#define MROWS 4096      // NB * S_LEN

typedef __bf16 bf16_t;
typedef __attribute__((ext_vector_type(8))) __bf16 bf16x8;
typedef __attribute__((ext_vector_type(4))) __bf16 bf16x4;
typedef __attribute__((ext_vector_type(4))) float f32x4;
typedef __attribute__((ext_vector_type(4))) float float4v;

__device__ __forceinline__ void gload_lds16(const bf16_t* g, bf16_t* l) {
  __builtin_amdgcn_global_load_lds(
      (const __attribute__((address_space(1))) void*)g,
      (__attribute__((address_space(3))) void*)l, 16, 0, 0);
}

// ---------------- convert f32 -> bf16 (contiguous) ----------------
__global__ __launch_bounds__(256) void convert_bf16(const float* __restrict__ in,
                                                    bf16_t* __restrict__ out, int n4) {
  int i = blockIdx.x * 256 + threadIdx.x;
  if (i >= n4) return;
  float4v v = *reinterpret_cast<const float4v*>(&in[(size_t)i * 4]);
  bf16x4 o;
  o[0] = (bf16_t)v[0]; o[1] = (bf16_t)v[1]; o[2] = (bf16_t)v[2]; o[3] = (bf16_t)v[3];
  *reinterpret_cast<bf16x4*>(&out[(size_t)i * 4]) = o;
}

// ---------------- fused transpose: all 8 weights in one launch ----------------
struct TrDesc { const float* src; bf16_t* dst; int K; int N; int nbx; int base; };
struct TrPack { TrDesc d[8]; };

__global__ __launch_bounds__(256) void transpose_all(TrPack p) {
  __shared__ float t[64][65];
  const int bid = blockIdx.x;
  int m = 0;
#pragma unroll
  for (int i = 1; i < 8; ++i) m += (bid >= p.d[i].base);
  const TrDesc td = p.d[m];
  const int local = bid - td.base;
  const int n0 = (local % td.nbx) * 64, k0 = (local / td.nbx) * 64;
  const int tx = threadIdx.x & 63, ty = threadIdx.x >> 6;
#pragma unroll
  for (int i = ty; i < 64; i += 4)
    t[i][tx] = td.src[(size_t)(k0 + i) * td.N + n0 + tx];
  __syncthreads();
#pragma unroll
  for (int i = ty; i < 64; i += 4)
    td.dst[(size_t)(n0 + i) * td.K + k0 + tx] = (bf16_t)t[tx][i];
}

// ---------------- GEMM: 128x128 tile, BK=64, double-buffered, counted vmcnt ----
// 4 waves (256 thr), per-wave 64x64 (acc[4][4]). LDS 2 x (A 16KB + B 16KB) = 64KB
// -> 2 blocks/CU (cross-block overlap, m114) AND counted-vmcnt pipeline:
//   bar1 (buf^1 free) -> stage(t+1 -> buf^1) -> vmcnt(8) (tile t landed, t+1 in
//   flight) -> bar2 (tile t visible) -> 32 MFMA @ setprio(1).
// A/B tiles XOR-swizzled (16B chunk ^= row&7; 128B rows): pre-swizzled GLOBAL
// source + linear LDS dest + swizzled read (verified 0-conflict in r9).
// MODE 1: f32 out + bias
// MODE 5: fused xb@[Wlq|Wkv|Wkr]; MODE 6: fused cq@[Wq|Wqr]; MODE 7: ckv@[Wk|Wv]
struct EpiParams {
  bf16_t* o0;
  bf16_t* o1;
  bf16_t* o2;
  float* outf;
  const float* bias;
  const float* cosb;
  const float* sinb;
};

template <int MODE>
__device__ __forceinline__ void gemm_body(const bf16_t* __restrict__ A,
                                          const bf16_t* __restrict__ Bt,
                                          int N, int K, int m0, int n0,
                                          bf16_t (*Ab)[128 * 64],
                                          bf16_t (*Bb)[128 * 64], EpiParams ep) {
  const int tid = threadIdx.x;
  const int lane = tid & 63, w = tid >> 6;    // 4 waves: 2M x 2N
  const int l15 = lane & 15, lg = lane >> 4;
  const int mw = (w >> 1) * 64, nw = (w & 1) * 64;
  const int nt = K >> 6;

  auto stage = [&](int t, int buf) {
    const int k0 = t << 6;
#pragma unroll
    for (int j = 0; j < 4; ++j) {             // A: 128 rows x 8 chunks = 1024 slots
      const int s = j * 256 + tid;
      const int row = s >> 3, c = s & 7;
      const int cs = c ^ (row & 7);
      gload_lds16(A + (size_t)(m0 + row) * K + k0 + cs * 8, &Ab[buf][s * 8]);
    }
#pragma unroll
    for (int j = 0; j < 4; ++j) {             // B: 128 rows x 8 chunks = 1024 slots
      const int s = j * 256 + tid;
      const int row = s >> 3, c = s & 7;
      const int cs = c ^ (row & 7);
      gload_lds16(Bt + (size_t)(n0 + row) * K + k0 + cs * 8, &Bb[buf][s * 8]);
    }
  };

  f32x4 acc[4][4] = {};
  stage(0, 0);                                // prologue: 8 loads in flight

  for (int t = 0; t < nt; ++t) {
    const int cur = t & 1;
    __builtin_amdgcn_s_barrier();             // all waves done compute(t-1) -> buf^1 free
    if (t + 1 < nt) {
      stage(t + 1, cur ^ 1);
      asm volatile("s_waitcnt vmcnt(8)" ::: "memory");  // own tile-t loads landed
    } else {
      asm volatile("s_waitcnt vmcnt(0)" ::: "memory");  // final tile drain
    }
    __builtin_amdgcn_s_barrier();             // every wave's tile-t loads landed
    __builtin_amdgcn_sched_barrier(0);

    __builtin_amdgcn_s_setprio(1);
#pragma unroll
    for (int kk = 0; kk < 2; ++kk) {
      const int c = kk * 4 + lg;
      bf16x8 a[4], b[4];
#pragma unroll
      for (int i = 0; i < 4; ++i) {
        const int r = mw + i * 16 + l15;
        a[i] = *reinterpret_cast<const bf16x8*>(&Ab[cur][r * 64 + ((c ^ (r & 7)) << 3)]);
      }
#pragma unroll
      for (int j = 0; j < 4; ++j) {
        const int r = nw + j * 16 + l15;
        b[j] = *reinterpret_cast<const bf16x8*>(&Bb[cur][r * 64 + ((c ^ (r & 7)) << 3)]);
      }
#pragma unroll
      for (int i = 0; i < 4; ++i)
#pragma unroll
        for (int j = 0; j < 4; ++j)
          acc[i][j] = __builtin_amdgcn_mfma_f32_16x16x32_bf16(a[i], b[j], acc[i][j], 0, 0, 0);
    }
    __builtin_amdgcn_s_setprio(0);
  }

#pragma unroll
  for (int i = 0; i < 4; ++i)
#pragma unroll
    for (int j = 0; j < 4; ++j) {
      const int col = n0 + nw + j * 16 + l15;
#pragma unroll
      for (int r = 0; r < 4; ++r) {
        const int row = m0 + mw + i * 16 + lg * 4 + r;
        float v = acc[i][j][r];
        const int b = row >> 11, s = row & 2047;
        if constexpr (MODE == 1) {
          ep.outf[(size_t)row * N + col] = v + ep.bias[col];
        } else if constexpr (MODE == 5) {
          if (col < 1536) {
            ep.o0[(size_t)row * 1536 + col] = (bf16_t)v;
          } else if (col < 2048) {
            ep.o1[(size_t)row * 512 + (col - 1536)] = (bf16_t)v;
          } else {
            const int c2 = col - 2048;
            float vb = v + ep.bias[c2];
            float other = __shfl_xor(vb, 1, 64);
            const int h = c2 >> 6, dr = c2 & 63;
            const int fi = dr >> 1;
            const float c = ep.cosb[s * 32 + fi];
            const float sn = ep.sinb[s * 32 + fi];
            const float o = (c2 & 1) ? (other * sn + vb * c) : (vb * c - other * sn);
            ep.o2[(((size_t)(b * NH + h)) * S_LEN + s) * DF + 128 + dr] = (bf16_t)o;
          }
        } else if constexpr (MODE == 6) {
          if (col < 2048) {
            const int h = col >> 7, d = col & 127;
            ep.o0[(((size_t)(b * NH + h)) * S_LEN + s) * DF + d] = (bf16_t)v;
          } else {
            const int c2 = col - 2048;
            float vb = v + ep.bias[c2];
            float other = __shfl_xor(vb, 1, 64);
            const int h = c2 >> 6, dr = c2 & 63;
            const int fi = dr >> 1;
            const float c = ep.cosb[s * 32 + fi];
            const float sn = ep.sinb[s * 32 + fi];
            const float o = (c2 & 1) ? (other * sn + vb * c) : (vb * c - other * sn);
            ep.o0[(((size_t)(b * NH + h)) * S_LEN + s) * DF + 128 + dr] = (bf16_t)o;
          }
        } else {  // MODE 7
          if (col < 2048) {
            const int h = col >> 7, d = col & 127;
            ep.o0[(((size_t)(b * NH + h)) * S_LEN + s) * DF + d] = (bf16_t)v;
          } else {
            const int c2 = col - 2048;
            const int h = c2 >> 7, d = c2 & 127;
            ep.o1[(((size_t)(b * NH + h)) * HDIM + d) * S_LEN + s] = (bf16_t)v;
          }
        }
      }
    }
}

template <int MODE>
__global__ __launch_bounds__(256, 2) void gemm_db(const bf16_t* __restrict__ A,
                                                  const bf16_t* __restrict__ Bt,
                                                  int N, int K, EpiParams ep) {
  __shared__ alignas(16) bf16_t Ab[2][128 * 64];
  __shared__ alignas(16) bf16_t Bb[2][128 * 64];
  const int nwg = gridDim.x;
  int f = blockIdx.x;
  f = (f & 7) * (nwg >> 3) + (f >> 3);        // T1 XCD swizzle (nwg % 8 == 0)
  const int nbx = N >> 7;
  const int m0 = (f / nbx) * 128, n0 = (f % nbx) * 128;
  gemm_body<MODE>(A, Bt, N, K, m0, n0, Ab, Bb, ep);
}

// Fused: blocks [0,768) MODE 6 (N=3072,K=1536); [768,1792) MODE 7 (N=4096,K=512).
__global__ __launch_bounds__(256, 2) void gemm_db67(const bf16_t* __restrict__ A6,
                                                    const bf16_t* __restrict__ Bt6,
                                                    const bf16_t* __restrict__ A7,
                                                    const bf16_t* __restrict__ Bt7,
                                                    EpiParams ep6, EpiParams ep7) {
  __shared__ alignas(16) bf16_t Ab[2][128 * 64];
  __shared__ alignas(16) bf16_t Bb[2][128 * 64];
  const int bid = blockIdx.x;
  if (bid < 768) {
    int f = (bid & 7) * 96 + (bid >> 3);
    const int m0 = (f / 24) * 128, n0 = (f % 24) * 128;
    gemm_body<6>(A6, Bt6, 3072, 1536, m0, n0, Ab, Bb, ep6);
  } else {
    int b2 = bid - 768;
    int f = (b2 & 7) * 128 + (b2 >> 3);
    const int m0 = (f / 32) * 128, n0 = (f % 32) * 128;
    gemm_body<7>(A7, Bt7, 4096, 512, m0, n0, Ab, Bb, ep7);
  }
}

// ---------------- flash attention (causal), swapped softmax, 32q/wave ----------------
// (unchanged from r8: 4 waves x 32 q-rows, swapped QK^T, defer-max, 56 KB LDS)
__global__ __launch_bounds__(256, 2) void attn_fwd(const bf16_t* __restrict__ qf,
                                                   const bf16_t* __restrict__ kf,
                                                   const bf16_t* __restrict__ vT,
                                                   bf16_t* __restrict__ att) {
  const int tid = threadIdx.x;
  const int lane = tid & 63, w = tid >> 6;   // w: 0..3
  const int l15 = lane & 15, lg = lane >> 4;
  const int l = blockIdx.x;                  // 0..511
  const int bh = (l & 7) * 4 + ((l >> 3) & 3);
  const int qchunk = l >> 5;                 // 0..15
  const int qb0 = (15 - qchunk) * 128;
  const int q0 = qb0 + w * 32;
  const float scale = 0.07216878364870322f;  // 1/sqrt(192)

  __shared__ alignas(16) bf16_t Ks[64 * 192];
  __shared__ alignas(16) bf16_t Vs[128 * 64];
  __shared__ alignas(16) bf16_t Ps[4 * 2048];

  bf16x8 qfr[2][6];
#pragma unroll
  for (int mf = 0; mf < 2; ++mf) {
    const bf16_t* qptr = qf + ((size_t)bh * S_LEN + q0 + mf * 16 + l15) * DF + lg * 8;
#pragma unroll
    for (int d = 0; d < 6; ++d)
      qfr[mf][d] = *reinterpret_cast<const bf16x8*>(qptr + d * 32);
  }

  f32x4 o[2][8] = {};
  float mrun[2] = {-1e30f, -1e30f}, lsum[2] = {0.0f, 0.0f};

  const bf16_t* kb0 = kf + (size_t)bh * S_LEN * DF;
  const bf16_t* vb0 = vT + (size_t)bh * HDIM * S_LEN;
  const int njt = qb0 / 64 + 2;
  const int wslot = tid & ~63;

  for (int jt = 0; jt < njt; ++jt) {
    const int j0 = jt * 64;
    __syncthreads();
    const bf16_t* kTile = kb0 + (size_t)j0 * DF;
#pragma unroll
    for (int i = 0; i < 6; ++i) {
      const int s = i * 256 + tid;
      const int row = s / 24;
      const int c = s - row * 24;
      const int cs = c ^ (row & 7);
      gload_lds16(kTile + (size_t)row * DF + cs * 8,
                  Ks + (size_t)(i * 256 + wslot) * 8);
    }
    const bf16_t* vTile = vb0 + j0;
#pragma unroll
    for (int i = 0; i < 4; ++i) {
      const int s = i * 256 + tid;
      const int row = s >> 3;
      const int c = s & 7;
      const int cs = c ^ (row & 7);
      gload_lds16(vTile + (size_t)row * S_LEN + cs * 8,
                  Vs + (size_t)(i * 256 + wslot) * 8);
    }
    __syncthreads();

    if (j0 > q0 + 31) continue;

    f32x4 sa[2][4] = {};
    __builtin_amdgcn_s_setprio(1);
#pragma unroll
    for (int jf = 0; jf < 4; ++jf) {
      const int krow = jf * 16 + l15;
      const int ksw = krow & 7;
#pragma unroll
      for (int d = 0; d < 6; ++d) {
        const int kc = (4 * d + lg) ^ ksw;
        bf16x8 kfr = *reinterpret_cast<const bf16x8*>(&Ks[krow * 192 + kc * 8]);
#pragma unroll
        for (int mf = 0; mf < 2; ++mf)
          sa[mf][jf] =
              __builtin_amdgcn_mfma_f32_16x16x32_bf16(kfr, qfr[mf][d], sa[mf][jf], 0, 0, 0);
      }
    }
    __builtin_amdgcn_s_setprio(0);

#pragma unroll
    for (int mf = 0; mf < 2; ++mf) {
      const int qi = q0 + mf * 16 + l15;
      const bool full = (j0 + 63 <= q0 + mf * 16);
      float sv[16];
#pragma unroll
      for (int jf = 0; jf < 4; ++jf)
#pragma unroll
        for (int r = 0; r < 4; ++r) {
          float x = sa[mf][jf][r] * scale;
          if (!full) {
            const int j = j0 + jf * 16 + lg * 4 + r;
            if (j > qi) x = -1e30f;
          }
          sv[jf * 4 + r] = x;
        }

      float a8[8];
#pragma unroll
      for (int i = 0; i < 8; ++i) a8[i] = fmaxf(sv[i], sv[i + 8]);
#pragma unroll
      for (int i = 0; i < 4; ++i) a8[i] = fmaxf(a8[i], a8[i + 4]);
      float mx = fmaxf(fmaxf(a8[0], a8[1]), fmaxf(a8[2], a8[3]));
      mx = fmaxf(mx, __shfl_xor(mx, 16, 64));
      mx = fmaxf(mx, __shfl_xor(mx, 32, 64));

      if (__any(mx > mrun[mf] + 8.0f)) {
        const float mn = fmaxf(mrun[mf], mx);
        const float alpha = __expf(mrun[mf] - mn);
        mrun[mf] = mn;
        lsum[mf] *= alpha;
        float af[4];
#pragma unroll
        for (int r = 0; r < 4; ++r) af[r] = __shfl(alpha, lg * 4 + r, 16);
#pragma unroll
        for (int dt = 0; dt < 8; ++dt)
#pragma unroll
          for (int r = 0; r < 4; ++r) o[mf][dt][r] *= af[r];
      }

#pragma unroll
      for (int i = 0; i < 16; ++i) sv[i] = __expf(sv[i] - mrun[mf]);
      float s8[8];
#pragma unroll
      for (int i = 0; i < 8; ++i) s8[i] = sv[i] + sv[i + 8];
#pragma unroll
      for (int i = 0; i < 4; ++i) s8[i] = s8[i] + s8[i + 4];
      float sm = (s8[0] + s8[1]) + (s8[2] + s8[3]);
      sm += __shfl_xor(sm, 16, 64);
      sm += __shfl_xor(sm, 32, 64);
      lsum[mf] += sm;

#pragma unroll
      for (int jf = 0; jf < 4; ++jf) {
        bf16x4 pk;
#pragma unroll
        for (int r = 0; r < 4; ++r) pk[r] = (bf16_t)sv[jf * 4 + r];
        const int key = jf * 16 + lg * 4;
        *reinterpret_cast<bf16x4*>(
            &Ps[w * 2048 + mf * 1024 + l15 * 64 + (key ^ ((l15 & 7) << 3))]) = pk;
      }
    }
    asm volatile("s_waitcnt lgkmcnt(0)" ::: "memory");
    __builtin_amdgcn_sched_barrier(0);
    bf16x8 pfr[2][2];
#pragma unroll
    for (int mf = 0; mf < 2; ++mf)
#pragma unroll
      for (int jk = 0; jk < 2; ++jk)
        pfr[mf][jk] = *reinterpret_cast<const bf16x8*>(
            &Ps[w * 2048 + mf * 1024 + l15 * 64 + (((jk * 4 + lg) ^ (l15 & 7)) << 3)]);

    __builtin_amdgcn_s_setprio(1);
#pragma unroll
    for (int dt = 0; dt < 8; ++dt) {
      const int vrow = dt * 16 + l15;
      const int vsw = vrow & 7;
#pragma unroll
      for (int jk = 0; jk < 2; ++jk) {
        const int vc = (jk * 4 + lg) ^ vsw;
        bf16x8 vfr = *reinterpret_cast<const bf16x8*>(&Vs[vrow * 64 + vc * 8]);
#pragma unroll
        for (int mf = 0; mf < 2; ++mf)
          o[mf][dt] =
              __builtin_amdgcn_mfma_f32_16x16x32_bf16(pfr[mf][jk], vfr, o[mf][dt], 0, 0, 0);
      }
    }
    __builtin_amdgcn_s_setprio(0);
  }

  const int b = bh >> 4, h = bh & 15;
#pragma unroll
  for (int mf = 0; mf < 2; ++mf) {
    const float inv = 1.0f / lsum[mf];
    float iv[4];
#pragma unroll
    for (int r = 0; r < 4; ++r) iv[r] = __shfl(inv, lg * 4 + r, 16);
#pragma unroll
    for (int dt = 0; dt < 8; ++dt)
#pragma unroll
      for (int r = 0; r < 4; ++r) {
        const int s = q0 + mf * 16 + lg * 4 + r;
        att[((size_t)b * S_LEN + s) * 2048 + h * 128 + dt * 16 + l15] =
            (bf16_t)(o[mf][dt][r] * iv[r]);
      }
  }
}

// ---------------- host launch ----------------
extern "C" void kernel_launch(void* const* d_in, const int* in_sizes, int n_in,
                              void* d_out, int out_size, void* d_ws, size_t ws_size,
                              hipStream_t stream) {
  const float* x    = (const float*)d_in[0];
  const float* fcos = (const float*)d_in[1];
  const float* fsin = (const float*)d_in[2];
  const float* Wkv  = (const float*)d_in[3];
  const float* Wlq  = (const float*)d_in[4];
  const float* Wq   = (const float*)d_in[5];
  const float* Wk   = (const float*)d_in[6];
  const float* Wv   = (const float*)d_in[7];
  const float* Wqr  = (const float*)d_in[8];
  const float* bqr  = (const float*)d_in[9];
  const float* Wkr  = (const float*)d_in[10];
  const float* bkr  = (const float*)d_in[11];
  const float* Wo   = (const float*)d_in[12];
  const float* bo   = (const float*)d_in[13];
  float* out = (float*)d_out;

  char* ws = (char*)d_ws;
  size_t off = 0;
  auto alloc = [&](size_t bytes) {
    void* p = ws + off;
    off += (bytes + 255) & ~(size_t)255;
    return p;
  };
  bf16_t* xb    = (bf16_t*)alloc((size_t)MROWS * 2048 * 2);
  bf16_t* WcatA = (bf16_t*)alloc((size_t)3072 * 2048 * 2);  // [Wlq|Wkv|Wkr]^T, K=2048
  bf16_t* WcatB = (bf16_t*)alloc((size_t)3072 * 1536 * 2);  // [Wq|Wqr]^T,     K=1536
  bf16_t* WcatC = (bf16_t*)alloc((size_t)4096 * 512 * 2);   // [Wk|Wv]^T,      K=512
  bf16_t* WoT   = (bf16_t*)alloc((size_t)2048 * 2048 * 2);
  bf16_t* cq    = (bf16_t*)alloc((size_t)MROWS * 1536 * 2);
  bf16_t* ckv   = (bf16_t*)alloc((size_t)MROWS * 512 * 2);
  bf16_t* qfb   = (bf16_t*)alloc((size_t)NB * NH * S_LEN * DF * 2);
  bf16_t* kfb   = (bf16_t*)alloc((size_t)NB * NH * S_LEN * DF * 2);
  bf16_t* vTb   = (bf16_t*)alloc((size_t)NB * NH * HDIM * S_LEN * 2);
  bf16_t* attb  = (bf16_t*)alloc((size_t)MROWS * 2048 * 2);

  // 1. convert x
  {
    int n4 = (MROWS * 2048) / 4;
    convert_bf16<<<dim3((n4 + 255) / 256), dim3(256), 0, stream>>>(x, xb, n4);
  }
  // 2. all 8 transposes in one launch
  {
    TrPack p;
    int base = 0;
    auto set = [&](int i, const float* s, bf16_t* d, int K, int N) {
      p.d[i] = {s, d, K, N, N / 64, base};
      base += (N / 64) * (K / 64);
    };
    set(0, Wlq, WcatA, 2048, 1536);
    set(1, Wkv, WcatA + (size_t)1536 * 2048, 2048, 512);
    set(2, Wkr, WcatA + (size_t)2048 * 2048, 2048, 1024);
    set(3, Wq,  WcatB, 1536, 2048);
    set(4, Wqr, WcatB + (size_t)2048 * 1536, 1536, 1024);
    set(5, Wk,  WcatC, 512, 2048);
    set(6, Wv,  WcatC + (size_t)2048 * 512, 512, 2048);
    set(7, Wo,  WoT, 2048, 2048);
    transpose_all<<<dim3(base), dim3(256), 0, stream>>>(p);
  }

  EpiParams ep{}, ep2{};

  // 3. fused: [cq | ckv | kr-rope->kf] = xb @ WcatA^T   (N=3072, K=2048)
  ep = {cq, ckv, kfb, nullptr, bkr, fcos, fsin};
  gemm_db<5><<<dim3(768), dim3(256), 0, stream>>>(xb, WcatA, 3072, 2048, ep);
  // 4+5. fused single launch: {q,qr->qf} and {k->kf, v->vT}
  ep  = {qfb, nullptr, nullptr, nullptr, bqr, fcos, fsin};
  ep2 = {kfb, vTb, nullptr, nullptr, nullptr, nullptr, nullptr};
  gemm_db67<<<dim3(1792), dim3(256), 0, stream>>>(cq, WcatB, ckv, WcatC, ep, ep2);
  // 6. attention
  attn_fwd<<<dim3(512), dim3(256), 0, stream>>>(qfb, kfb, vTb, attb);
  // 7. out = att @ Wo + bo  (f32)
  ep = {nullptr, nullptr, nullptr, out, bo, nullptr, nullptr};
  gemm_db<1><<<dim3(512), dim3(256), 0, stream>>>(attb, WoT, 2048, 2048, ep);
}